// Round 13
// baseline (224.813 us; speedup 1.0000x reference)
//
#include <hip/hip_runtime.h>
#include <hip/hip_bf16.h>

#define N_NODES 50000
#define N_EDGES 800000
#define M_IN 512
#define H_OUT 512

typedef __attribute__((ext_vector_type(8))) short    bf16x8;  // MFMA A/B frag (4 VGPR)
typedef __attribute__((ext_vector_type(4))) float    f32x4;   // MFMA C/D frag
typedef __attribute__((ext_vector_type(8))) unsigned short u16x8;

__device__ inline float bf2f(unsigned short u) {
    unsigned int x = ((unsigned int)u) << 16;
    return __builtin_bit_cast(float, x);
}
__device__ inline unsigned short f2bf(float f) {   // round-to-nearest-even
    unsigned int x = __builtin_bit_cast(unsigned int, f);
    return (unsigned short)((x + 0x7FFF + ((x >> 16) & 1)) >> 16);
}
__device__ inline void gload_lds16(const void* g, void* lds) {
    __builtin_amdgcn_global_load_lds(
        (const __attribute__((address_space(1))) void*)g,
        (__attribute__((address_space(3))) void*)lds, 16, 0, 0);
}
__device__ inline int wave_incl_scan(int x, int lane) {
#pragma unroll
    for (int d = 1; d < 64; d <<= 1) {
        int y = __shfl_up(x, d, 64);
        if (lane >= d) x += y;
    }
    return x;
}

// ---------------------------------------------------------------------------
// convx v2 (split out of prep): int8 row-scaled quant with forced ILP.
// 2 rows per wave; all 4 float4 loads issued up-front (64 B/lane in flight);
// two INDEPENDENT shfl-reduce chains interleaved; quant+pack+store both rows.
// ---------------------------------------------------------------------------
__global__ __launch_bounds__(256) void convx_kernel(
    const float* __restrict__ X, unsigned char* __restrict__ Xq,
    float* __restrict__ sc)
{
    const int r0 = (blockIdx.x * 4 + (threadIdx.x >> 6)) * 2;  // 6250*4*2 = 50000
    const int l  = threadIdx.x & 63;

    const float4 a0 = *(const float4*)(X + (size_t)r0 * M_IN + l * 8);
    const float4 b0 = *(const float4*)(X + (size_t)r0 * M_IN + l * 8 + 4);
    const float4 a1 = *(const float4*)(X + (size_t)(r0 + 1) * M_IN + l * 8);
    const float4 b1 = *(const float4*)(X + (size_t)(r0 + 1) * M_IN + l * 8 + 4);

    float m0 = fmaxf(fmaxf(fmaxf(fabsf(a0.x), fabsf(a0.y)), fmaxf(fabsf(a0.z), fabsf(a0.w))),
                     fmaxf(fmaxf(fabsf(b0.x), fabsf(b0.y)), fmaxf(fabsf(b0.z), fabsf(b0.w))));
    float m1 = fmaxf(fmaxf(fmaxf(fabsf(a1.x), fabsf(a1.y)), fmaxf(fabsf(a1.z), fabsf(a1.w))),
                     fmaxf(fmaxf(fabsf(b1.x), fabsf(b1.y)), fmaxf(fabsf(b1.z), fabsf(b1.w))));
#pragma unroll
    for (int d = 1; d < 64; d <<= 1) {        // interleaved independent chains
        m0 = fmaxf(m0, __shfl_xor(m0, d, 64));
        m1 = fmaxf(m1, __shfl_xor(m1, d, 64));
    }
    const float inv0 = (m0 > 0.f) ? 127.f / m0 : 0.f;
    const float inv1 = (m1 > 0.f) ? 127.f / m1 : 0.f;

    const float xs0[8] = {a0.x, a0.y, a0.z, a0.w, b0.x, b0.y, b0.z, b0.w};
    const float xs1[8] = {a1.x, a1.y, a1.z, a1.w, b1.x, b1.y, b1.z, b1.w};
    unsigned int u0[8], u1[8];
#pragma unroll
    for (int j = 0; j < 8; ++j) {
        int q0 = __float2int_rn(xs0[j] * inv0) + 128;
        int q1 = __float2int_rn(xs1[j] * inv1) + 128;
        u0[j] = (unsigned int)max(0, min(255, q0));
        u1[j] = (unsigned int)max(0, min(255, q1));
    }
    uint2 w0, w1;
    w0.x = u0[0] | (u0[1] << 8) | (u0[2] << 16) | (u0[3] << 24);
    w0.y = u0[4] | (u0[5] << 8) | (u0[6] << 16) | (u0[7] << 24);
    w1.x = u1[0] | (u1[1] << 8) | (u1[2] << 16) | (u1[3] << 24);
    w1.y = u1[4] | (u1[5] << 8) | (u1[6] << 16) | (u1[7] << 24);
    *(uint2*)(Xq + (size_t)r0 * M_IN + l * 8)       = w0;
    *(uint2*)(Xq + (size_t)(r0 + 1) * M_IN + l * 8) = w1;
    if (l == 0) sc[r0] = m0 * (1.f / 127.f);
    if (l == 1) sc[r0 + 1] = m1 * (1.f / 127.f);
}

// ---------------------------------------------------------------------------
// misc: convw (blocks [0,1024)) + privatized hist (rest).
// ---------------------------------------------------------------------------
#define CONVW_B 1024
#define HIST_B  3125
#define HPAD    50048    // padded node stride for replicas (16B aligned)

__global__ __launch_bounds__(256) void misc_kernel(
    const float* __restrict__ W, unsigned short* __restrict__ Wt,
    const int* __restrict__ edst, int* __restrict__ hrep)
{
    const int b = blockIdx.x;
    if (b < CONVW_B) {
        const int id = b * 256 + threadIdx.x;                  // 262144 = 512*512
        const int n = id >> 9, k = id & 511;
        Wt[(size_t)n * 512 + k] = f2bf(W[(size_t)k * 512 + n]);
    } else {
        const int e = (b - CONVW_B) * 256 + threadIdx.x;       // 800000 exact
        atomicAdd(&hrep[(size_t)(b & 7) * HPAD + edst[e]], 1);
    }
}

// ---------------------------------------------------------------------------
// Hierarchical scan. scan1 sums the 8 histogram replicas -> counts + bsum.
// scan3 leaves cursor[i] = offs[i] (build needs only one atomic per edge).
// ---------------------------------------------------------------------------
#define SCAN_B ((N_NODES + 255) / 256)   // 196

__global__ __launch_bounds__(256) void scan1_kernel(
    const int* __restrict__ hrep, int* __restrict__ counts, int* __restrict__ bsum)
{
    const int i = blockIdx.x * 256 + threadIdx.x;
    int v = 0;
    if (i < N_NODES) {
#pragma unroll
        for (int r = 0; r < 8; ++r) v += hrep[(size_t)r * HPAD + i];
        counts[i] = v;
    }
#pragma unroll
    for (int d = 1; d < 64; d <<= 1) v += __shfl_xor(v, d, 64);
    __shared__ int ws[4];
    if ((threadIdx.x & 63) == 0) ws[threadIdx.x >> 6] = v;
    __syncthreads();
    if (threadIdx.x == 0) bsum[blockIdx.x] = ws[0] + ws[1] + ws[2] + ws[3];
}

__global__ __launch_bounds__(256) void scan3_kernel(
    int* __restrict__ counts, const int* __restrict__ bsum, int* __restrict__ offs)
{
    const int tid = threadIdx.x, lane = tid & 63, wv = tid >> 6;

    int p = 0;
    for (int j = tid; j < blockIdx.x; j += 256) p += bsum[j];
#pragma unroll
    for (int d = 1; d < 64; d <<= 1) p += __shfl_xor(p, d, 64);
    __shared__ int wred[4];
    if (lane == 0) wred[wv] = p;
    __syncthreads();
    const int bpre = wred[0] + wred[1] + wred[2] + wred[3];

    const int i = blockIdx.x * 256 + tid;
    int c = (i < N_NODES) ? counts[i] : 0;
    int inc = wave_incl_scan(c, lane);
    __shared__ int ws[4];
    if (lane == 63) ws[wv] = inc;
    __syncthreads();
    if (tid == 0) {
        int run = 0;
#pragma unroll
        for (int k = 0; k < 4; ++k) { int t = ws[k]; ws[k] = run; run += t; }
    }
    __syncthreads();
    const int excl = bpre + ws[wv] + inc - c;
    if (i < N_NODES) {
        offs[i]   = excl;
        counts[i] = excl;                               // cursor starts at offs
        if (i == N_NODES - 1) offs[N_NODES] = excl + c; // == N_EDGES
    }
}

// build: packed edge = (src16 << 16) | bf16(val); single atomic per edge.
__global__ __launch_bounds__(256) void build_kernel(
    const int* __restrict__ esrc, const int* __restrict__ edst,
    const float* __restrict__ eval,
    int* __restrict__ cursor, unsigned int* __restrict__ pairs)
{
    const int e = blockIdx.x * 256 + threadIdx.x;
    if (e >= N_EDGES) return;
    const int pos = atomicAdd(&cursor[edst[e]], 1);
    pairs[pos] = ((unsigned int)esrc[e] << 16) | (unsigned int)f2bf(eval[e]);
}

// ---------------------------------------------------------------------------
// Gather (int8 X, round-11 champion): ONE wave per node, 8 cols/lane
// (uint2 = 8 u8), 512 B row-read per edge. Dequant via running-S trick.
// fp32 accum, bf16 out.
// ---------------------------------------------------------------------------
__global__ __launch_bounds__(256) void gather_kernel(
    const unsigned char* __restrict__ Xq,
    const float*        __restrict__ sc,
    const int*          __restrict__ offs,
    const unsigned int* __restrict__ pairs,
    unsigned short*     __restrict__ Yb)
{
    const int node = blockIdx.x * 4 + (threadIdx.x >> 6);  // 12500*4 = 50000 exact
    const int lane = threadIdx.x & 63;

    const int beg = offs[node];
    const int end = offs[node + 1];
    const int col = lane * 8;                              // 8 cols per lane

    float acc[8] = {};
    float S = 0.f;

    int e = beg;
    for (; e + 3 < end; e += 4) {
        const unsigned int k0 = pairs[e],     k1 = pairs[e + 1];
        const unsigned int k2 = pairs[e + 2], k3 = pairs[e + 3];
        const uint2 x0 = *(const uint2*)(Xq + (size_t)(k0 >> 16) * M_IN + col);
        const uint2 x1 = *(const uint2*)(Xq + (size_t)(k1 >> 16) * M_IN + col);
        const uint2 x2 = *(const uint2*)(Xq + (size_t)(k2 >> 16) * M_IN + col);
        const uint2 x3 = *(const uint2*)(Xq + (size_t)(k3 >> 16) * M_IN + col);
        const float f0 = bf2f((unsigned short)(k0 & 0xffffu)) * sc[k0 >> 16];
        const float f1 = bf2f((unsigned short)(k1 & 0xffffu)) * sc[k1 >> 16];
        const float f2 = bf2f((unsigned short)(k2 & 0xffffu)) * sc[k2 >> 16];
        const float f3 = bf2f((unsigned short)(k3 & 0xffffu)) * sc[k3 >> 16];
        S += f0 + f1 + f2 + f3;
#pragma unroll
        for (int j = 0; j < 4; ++j) {
            acc[j]     += (float)((x0.x >> (8 * j)) & 0xffu) * f0
                        + (float)((x1.x >> (8 * j)) & 0xffu) * f1
                        + (float)((x2.x >> (8 * j)) & 0xffu) * f2
                        + (float)((x3.x >> (8 * j)) & 0xffu) * f3;
            acc[4 + j] += (float)((x0.y >> (8 * j)) & 0xffu) * f0
                        + (float)((x1.y >> (8 * j)) & 0xffu) * f1
                        + (float)((x2.y >> (8 * j)) & 0xffu) * f2
                        + (float)((x3.y >> (8 * j)) & 0xffu) * f3;
        }
    }
    for (; e < end; ++e) {
        const unsigned int k0 = pairs[e];
        const uint2 x0 = *(const uint2*)(Xq + (size_t)(k0 >> 16) * M_IN + col);
        const float f0 = bf2f((unsigned short)(k0 & 0xffffu)) * sc[k0 >> 16];
        S += f0;
#pragma unroll
        for (int j = 0; j < 4; ++j) {
            acc[j]     += (float)((x0.x >> (8 * j)) & 0xffu) * f0;
            acc[4 + j] += (float)((x0.y >> (8 * j)) & 0xffu) * f0;
        }
    }

    u16x8 o;
#pragma unroll
    for (int j = 0; j < 8; ++j) o[j] = f2bf(acc[j] - 128.f * S);
    *(u16x8*)(Yb + (size_t)node * M_IN + col) = o;
}

// ---------------------------------------------------------------------------
// out = relu(Yb @ Wt^T) — bf16 MFMA 16x16x32, fp32 accum. (unchanged)
// 128x128 tile, BK=32, 4 waves, 2-phase pipeline, XCD-swizzled 1-D grid.
// ---------------------------------------------------------------------------
#define BM 128
#define BN 128
#define BK 32
#define NT (M_IN / BK)   // 16
#define ROWT ((N_NODES + BM - 1) / BM)   // 391
#define GEMM_GRID (((ROWT + 7) / 8) * 8 * 4)   // 1568, divisible by 8

__global__ __launch_bounds__(256, 2) void gemm_mfma_kernel(
    const unsigned short* __restrict__ Yb,
    const unsigned short* __restrict__ Wt,
    float* __restrict__ out)
{
    const int bid = blockIdx.x;
    const int s   = bid >> 3;
    const int r   = (s >> 2) * 8 + (bid & 7);
    if (r >= ROWT) return;
    const int row0 = r * BM;
    const int col0 = (s & 3) * BN;

    __shared__ unsigned short As[2][BM * BK];  // 2 x 8 KB
    __shared__ unsigned short Bs[2][BN * BK];  // 2 x 8 KB

    const int tid  = threadIdx.x;
    const int lane = tid & 63;
    const int wid  = tid >> 6;
    const int wr   = wid >> 1;
    const int wc   = wid & 1;

    f32x4 acc[4][4] = {};

    int srow[2], ksw[2], ldsb[2];
#pragma unroll
    for (int i = 0; i < 2; ++i) {
        const int b   = (i * 256 + tid) * 16;
        const int row = b >> 6;
        const int cir = (b >> 4) & 3;
        srow[i] = row;
        ksw[i]  = (cir ^ ((row >> 1) & 3)) << 3;
        ldsb[i] = b;
    }
    int agr[2];
#pragma unroll
    for (int i = 0; i < 2; ++i) {
        int gr = row0 + srow[i];
        if (gr >= N_NODES) gr = N_NODES - 1;
        agr[i] = gr;
    }

    int abyte[4], bbyte[4];
    const int c = lane >> 4;
#pragma unroll
    for (int m = 0; m < 4; ++m) {
        const int ra = wr * 64 + m * 16 + (lane & 15);
        abyte[m] = ra * 64 + ((c ^ ((ra >> 1) & 3)) << 4);
        const int rb = wc * 64 + m * 16 + (lane & 15);
        bbyte[m] = rb * 64 + ((c ^ ((rb >> 1) & 3)) << 4);
    }

#define STAGE(buf, k0)                                                          \
    do {                                                                        \
        _Pragma("unroll")                                                       \
        for (int i = 0; i < 2; ++i) {                                           \
            gload_lds16(Yb + (size_t)agr[i] * M_IN + (k0) + ksw[i],             \
                        (char*)As[buf] + ldsb[i]);                              \
            gload_lds16(Wt + (size_t)(col0 + srow[i]) * M_IN + (k0) + ksw[i],   \
                        (char*)Bs[buf] + ldsb[i]);                              \
        }                                                                       \
    } while (0)

    STAGE(0, 0);
    asm volatile("s_waitcnt vmcnt(0)" ::: "memory");
    __builtin_amdgcn_s_barrier();

    int cur = 0;
    for (int t = 0; t < NT; ++t) {
        if (t + 1 < NT) STAGE(cur ^ 1, (t + 1) * BK);

        bf16x8 af[4], bfr[4];
#pragma unroll
        for (int m = 0; m < 4; ++m)
            af[m]  = *(const bf16x8*)((const char*)As[cur] + abyte[m]);
#pragma unroll
        for (int n = 0; n < 4; ++n)
            bfr[n] = *(const bf16x8*)((const char*)Bs[cur] + bbyte[n]);

#pragma unroll
        for (int m = 0; m < 4; ++m)
#pragma unroll
            for (int n = 0; n < 4; ++n)
                acc[m][n] = __builtin_amdgcn_mfma_f32_16x16x32_bf16(
                    af[m], bfr[n], acc[m][n], 0, 0, 0);

        if (t + 1 < NT) {
            asm volatile("s_waitcnt vmcnt(0)" ::: "memory");
            __builtin_amdgcn_s_barrier();
        }
        cur ^= 1;
    }
#undef STAGE

    // epilogue: C/D map col=lane&15, row=(lane>>4)*4+r  [measured m89]
#pragma unroll
    for (int m = 0; m < 4; ++m) {
#pragma unroll
        for (int n = 0; n < 4; ++n) {
#pragma unroll
            for (int rr = 0; rr < 4; ++rr) {
                const int row = row0 + wr * 64 + m * 16 + (lane >> 4) * 4 + rr;
                const int col = col0 + wc * 64 + n * 16 + (lane & 15);
                if (row < N_NODES)
                    out[(size_t)row * H_OUT + col] = fmaxf(acc[m][n][rr], 0.f);
            }
        }
    }
}

extern "C" void kernel_launch(void* const* d_in, const int* in_sizes, int n_in,
                              void* d_out, int out_size, void* d_ws, size_t ws_size,
                              hipStream_t stream) {
    const float* X    = (const float*)d_in[0];
    const float* W    = (const float*)d_in[1];
    const int*   esrc = (const int*)d_in[2];
    const int*   edst = (const int*)d_in[3];
    const float* eval = (const float*)d_in[4];
    float* out = (float*)d_out;

    // workspace layout (16B-aligned)
    char* w = (char*)d_ws;
    unsigned short* Yb = (unsigned short*)w;  w += (size_t)N_NODES * M_IN * 2;  // 51.2 MB
    unsigned char*  Xq = (unsigned char*)w;   w += (size_t)N_NODES * M_IN;      // 25.6 MB
    float*          sc = (float*)w;           w += (size_t)N_NODES * 4;         // 200 KB
    unsigned short* Wt = (unsigned short*)w;  w += (size_t)M_IN * H_OUT * 2;    // 0.5 MB
    int*   offs   = (int*)w;                  w += (size_t)(N_NODES + 4) * 4;   // 16B align
    int*   cursor = (int*)w;                  w += (size_t)N_NODES * 4;
    int*   bsum   = (int*)w;                  w += (size_t)((SCAN_B + 3) & ~3) * 4;
    int*   hrep   = (int*)w;                  w += (size_t)8 * HPAD * 4;        // 1.6 MB
    unsigned int* pairs = (unsigned int*)w;                                     // 3.2 MB

    hipMemsetAsync(hrep, 0, (size_t)8 * HPAD * sizeof(int), stream);

    convx_kernel<<<6250, 256, 0, stream>>>(X, Xq, sc);

    misc_kernel<<<CONVW_B + HIST_B, 256, 0, stream>>>(W, Wt, edst, hrep);

    scan1_kernel<<<SCAN_B, 256, 0, stream>>>(hrep, cursor, bsum);
    scan3_kernel<<<SCAN_B, 256, 0, stream>>>(cursor, bsum, offs);  // cursor := offs

    build_kernel<<<(N_EDGES + 255) / 256, 256, 0, stream>>>(
        esrc, edst, eval, cursor, pairs);

    // one wave per node: 12500 blocks x 4 waves
    gather_kernel<<<(N_NODES + 3) / 4, 256, 0, stream>>>(Xq, sc, offs, pairs, Yb);

    gemm_mfma_kernel<<<GEMM_GRID, 256, 0, stream>>>(Yb, Wt, out);
}

// Round 14
// 214.863 us; speedup vs baseline: 1.0463x; 1.0463x over previous
//
#include <hip/hip_runtime.h>
#include <hip/hip_bf16.h>

#define N_NODES 50000
#define N_EDGES 800000
#define M_IN 512
#define H_OUT 512

typedef __attribute__((ext_vector_type(8))) short    bf16x8;  // MFMA A/B frag (4 VGPR)
typedef __attribute__((ext_vector_type(4))) float    f32x4;   // MFMA C/D frag
typedef __attribute__((ext_vector_type(8))) unsigned short u16x8;

__device__ inline float bf2f(unsigned short u) {
    unsigned int x = ((unsigned int)u) << 16;
    return __builtin_bit_cast(float, x);
}
__device__ inline unsigned short f2bf(float f) {   // round-to-nearest-even
    unsigned int x = __builtin_bit_cast(unsigned int, f);
    return (unsigned short)((x + 0x7FFF + ((x >> 16) & 1)) >> 16);
}
__device__ inline void gload_lds16(const void* g, void* lds) {
    __builtin_amdgcn_global_load_lds(
        (const __attribute__((address_space(1))) void*)g,
        (__attribute__((address_space(3))) void*)lds, 16, 0, 0);
}
__device__ inline int wave_incl_scan(int x, int lane) {
#pragma unroll
    for (int d = 1; d < 64; d <<= 1) {
        int y = __shfl_up(x, d, 64);
        if (lane >= d) x += y;
    }
    return x;
}

// ---------------------------------------------------------------------------
// prep (re-fused): convx-v2 ILP quant (blocks [0,6250)) + convw + hist-8rep.
// convx: 2 rows/wave, 4 loads up-front, interleaved reduce chains.
// ---------------------------------------------------------------------------
#define CONVX_B 6250
#define CONVW_B 1024
#define HIST_B  3125
#define HPAD    50048    // padded node stride for replicas (16B aligned)

__global__ __launch_bounds__(256) void prep_kernel(
    const float* __restrict__ X, unsigned char* __restrict__ Xq,
    float* __restrict__ sc,
    const float* __restrict__ W, unsigned short* __restrict__ Wt,
    const int* __restrict__ edst, int* __restrict__ hrep)
{
    const int b = blockIdx.x;
    if (b < CONVX_B) {
        const int r0 = (b * 4 + (threadIdx.x >> 6)) * 2;   // 6250*4*2 = 50000
        const int l  = threadIdx.x & 63;

        const float4 a0 = *(const float4*)(X + (size_t)r0 * M_IN + l * 8);
        const float4 b0 = *(const float4*)(X + (size_t)r0 * M_IN + l * 8 + 4);
        const float4 a1 = *(const float4*)(X + (size_t)(r0 + 1) * M_IN + l * 8);
        const float4 b1 = *(const float4*)(X + (size_t)(r0 + 1) * M_IN + l * 8 + 4);

        float m0 = fmaxf(fmaxf(fmaxf(fabsf(a0.x), fabsf(a0.y)), fmaxf(fabsf(a0.z), fabsf(a0.w))),
                         fmaxf(fmaxf(fabsf(b0.x), fabsf(b0.y)), fmaxf(fabsf(b0.z), fabsf(b0.w))));
        float m1 = fmaxf(fmaxf(fmaxf(fabsf(a1.x), fabsf(a1.y)), fmaxf(fabsf(a1.z), fabsf(a1.w))),
                         fmaxf(fmaxf(fabsf(b1.x), fabsf(b1.y)), fmaxf(fabsf(b1.z), fabsf(b1.w))));
#pragma unroll
        for (int d = 1; d < 64; d <<= 1) {
            m0 = fmaxf(m0, __shfl_xor(m0, d, 64));
            m1 = fmaxf(m1, __shfl_xor(m1, d, 64));
        }
        const float inv0 = (m0 > 0.f) ? 127.f / m0 : 0.f;
        const float inv1 = (m1 > 0.f) ? 127.f / m1 : 0.f;

        const float xs0[8] = {a0.x, a0.y, a0.z, a0.w, b0.x, b0.y, b0.z, b0.w};
        const float xs1[8] = {a1.x, a1.y, a1.z, a1.w, b1.x, b1.y, b1.z, b1.w};
        unsigned int u0[8], u1[8];
#pragma unroll
        for (int j = 0; j < 8; ++j) {
            int q0 = __float2int_rn(xs0[j] * inv0) + 128;
            int q1 = __float2int_rn(xs1[j] * inv1) + 128;
            u0[j] = (unsigned int)max(0, min(255, q0));
            u1[j] = (unsigned int)max(0, min(255, q1));
        }
        uint2 w0, w1;
        w0.x = u0[0] | (u0[1] << 8) | (u0[2] << 16) | (u0[3] << 24);
        w0.y = u0[4] | (u0[5] << 8) | (u0[6] << 16) | (u0[7] << 24);
        w1.x = u1[0] | (u1[1] << 8) | (u1[2] << 16) | (u1[3] << 24);
        w1.y = u1[4] | (u1[5] << 8) | (u1[6] << 16) | (u1[7] << 24);
        *(uint2*)(Xq + (size_t)r0 * M_IN + l * 8)       = w0;
        *(uint2*)(Xq + (size_t)(r0 + 1) * M_IN + l * 8) = w1;
        if (l == 0) sc[r0] = m0 * (1.f / 127.f);
        if (l == 1) sc[r0 + 1] = m1 * (1.f / 127.f);
    } else if (b < CONVX_B + CONVW_B) {
        const int id = (b - CONVX_B) * 256 + threadIdx.x;      // 262144 = 512*512
        const int n = id >> 9, k = id & 511;
        Wt[(size_t)n * 512 + k] = f2bf(W[(size_t)k * 512 + n]);
    } else {
        const int e = (b - CONVX_B - CONVW_B) * 256 + threadIdx.x;  // 800000 exact
        atomicAdd(&hrep[(size_t)(b & 7) * HPAD + edst[e]], 1);
    }
}

// ---------------------------------------------------------------------------
// Hierarchical scan. scan1 sums the 8 histogram replicas -> counts + bsum.
// scan3 leaves cursor[i] = offs[i] (build needs only one atomic per edge).
// ---------------------------------------------------------------------------
#define SCAN_B ((N_NODES + 255) / 256)   // 196

__global__ __launch_bounds__(256) void scan1_kernel(
    const int* __restrict__ hrep, int* __restrict__ counts, int* __restrict__ bsum)
{
    const int i = blockIdx.x * 256 + threadIdx.x;
    int v = 0;
    if (i < N_NODES) {
#pragma unroll
        for (int r = 0; r < 8; ++r) v += hrep[(size_t)r * HPAD + i];
        counts[i] = v;
    }
#pragma unroll
    for (int d = 1; d < 64; d <<= 1) v += __shfl_xor(v, d, 64);
    __shared__ int ws[4];
    if ((threadIdx.x & 63) == 0) ws[threadIdx.x >> 6] = v;
    __syncthreads();
    if (threadIdx.x == 0) bsum[blockIdx.x] = ws[0] + ws[1] + ws[2] + ws[3];
}

__global__ __launch_bounds__(256) void scan3_kernel(
    int* __restrict__ counts, const int* __restrict__ bsum, int* __restrict__ offs)
{
    const int tid = threadIdx.x, lane = tid & 63, wv = tid >> 6;

    int p = 0;
    for (int j = tid; j < blockIdx.x; j += 256) p += bsum[j];
#pragma unroll
    for (int d = 1; d < 64; d <<= 1) p += __shfl_xor(p, d, 64);
    __shared__ int wred[4];
    if (lane == 0) wred[wv] = p;
    __syncthreads();
    const int bpre = wred[0] + wred[1] + wred[2] + wred[3];

    const int i = blockIdx.x * 256 + tid;
    int c = (i < N_NODES) ? counts[i] : 0;
    int inc = wave_incl_scan(c, lane);
    __shared__ int ws[4];
    if (lane == 63) ws[wv] = inc;
    __syncthreads();
    if (tid == 0) {
        int run = 0;
#pragma unroll
        for (int k = 0; k < 4; ++k) { int t = ws[k]; ws[k] = run; run += t; }
    }
    __syncthreads();
    const int excl = bpre + ws[wv] + inc - c;
    if (i < N_NODES) {
        offs[i]   = excl;
        counts[i] = excl;                               // cursor starts at offs
        if (i == N_NODES - 1) offs[N_NODES] = excl + c; // == N_EDGES
    }
}

// build: packed edge = (src16 << 16) | bf16(val); single atomic per edge.
__global__ __launch_bounds__(256) void build_kernel(
    const int* __restrict__ esrc, const int* __restrict__ edst,
    const float* __restrict__ eval,
    int* __restrict__ cursor, unsigned int* __restrict__ pairs)
{
    const int e = blockIdx.x * 256 + threadIdx.x;
    if (e >= N_EDGES) return;
    const int pos = atomicAdd(&cursor[edst[e]], 1);
    pairs[pos] = ((unsigned int)esrc[e] << 16) | (unsigned int)f2bf(eval[e]);
}

// ---------------------------------------------------------------------------
// Gather (int8 X, round-11 champion): ONE wave per node, 8 cols/lane
// (uint2 = 8 u8), 512 B row-read per edge. Dequant via running-S trick.
// fp32 accum, bf16 out.
// ---------------------------------------------------------------------------
__global__ __launch_bounds__(256) void gather_kernel(
    const unsigned char* __restrict__ Xq,
    const float*        __restrict__ sc,
    const int*          __restrict__ offs,
    const unsigned int* __restrict__ pairs,
    unsigned short*     __restrict__ Yb)
{
    const int node = blockIdx.x * 4 + (threadIdx.x >> 6);  // 12500*4 = 50000 exact
    const int lane = threadIdx.x & 63;

    const int beg = offs[node];
    const int end = offs[node + 1];
    const int col = lane * 8;                              // 8 cols per lane

    float acc[8] = {};
    float S = 0.f;

    int e = beg;
    for (; e + 3 < end; e += 4) {
        const unsigned int k0 = pairs[e],     k1 = pairs[e + 1];
        const unsigned int k2 = pairs[e + 2], k3 = pairs[e + 3];
        const uint2 x0 = *(const uint2*)(Xq + (size_t)(k0 >> 16) * M_IN + col);
        const uint2 x1 = *(const uint2*)(Xq + (size_t)(k1 >> 16) * M_IN + col);
        const uint2 x2 = *(const uint2*)(Xq + (size_t)(k2 >> 16) * M_IN + col);
        const uint2 x3 = *(const uint2*)(Xq + (size_t)(k3 >> 16) * M_IN + col);
        const float f0 = bf2f((unsigned short)(k0 & 0xffffu)) * sc[k0 >> 16];
        const float f1 = bf2f((unsigned short)(k1 & 0xffffu)) * sc[k1 >> 16];
        const float f2 = bf2f((unsigned short)(k2 & 0xffffu)) * sc[k2 >> 16];
        const float f3 = bf2f((unsigned short)(k3 & 0xffffu)) * sc[k3 >> 16];
        S += f0 + f1 + f2 + f3;
#pragma unroll
        for (int j = 0; j < 4; ++j) {
            acc[j]     += (float)((x0.x >> (8 * j)) & 0xffu) * f0
                        + (float)((x1.x >> (8 * j)) & 0xffu) * f1
                        + (float)((x2.x >> (8 * j)) & 0xffu) * f2
                        + (float)((x3.x >> (8 * j)) & 0xffu) * f3;
            acc[4 + j] += (float)((x0.y >> (8 * j)) & 0xffu) * f0
                        + (float)((x1.y >> (8 * j)) & 0xffu) * f1
                        + (float)((x2.y >> (8 * j)) & 0xffu) * f2
                        + (float)((x3.y >> (8 * j)) & 0xffu) * f3;
        }
    }
    for (; e < end; ++e) {
        const unsigned int k0 = pairs[e];
        const uint2 x0 = *(const uint2*)(Xq + (size_t)(k0 >> 16) * M_IN + col);
        const float f0 = bf2f((unsigned short)(k0 & 0xffffu)) * sc[k0 >> 16];
        S += f0;
#pragma unroll
        for (int j = 0; j < 4; ++j) {
            acc[j]     += (float)((x0.x >> (8 * j)) & 0xffu) * f0;
            acc[4 + j] += (float)((x0.y >> (8 * j)) & 0xffu) * f0;
        }
    }

    u16x8 o;
#pragma unroll
    for (int j = 0; j < 8; ++j) o[j] = f2bf(acc[j] - 128.f * S);
    *(u16x8*)(Yb + (size_t)node * M_IN + col) = o;
}

// ---------------------------------------------------------------------------
// out = relu(Yb @ Wt^T) — bf16 MFMA 16x16x32, fp32 accum.
// 128x128 tile, BK=32, 4 waves, 2-phase pipeline, XCD-swizzled 1-D grid.
// NEW: __launch_bounds__(256, 4) -> 4 blocks/CU (was 2; occupancy was 32%,
// not enough resident blocks to cover the per-tile vmcnt(0) drain).
// ---------------------------------------------------------------------------
#define BM 128
#define BN 128
#define BK 32
#define NT (M_IN / BK)   // 16
#define ROWT ((N_NODES + BM - 1) / BM)   // 391
#define GEMM_GRID (((ROWT + 7) / 8) * 8 * 4)   // 1568, divisible by 8

__global__ __launch_bounds__(256, 4) void gemm_mfma_kernel(
    const unsigned short* __restrict__ Yb,
    const unsigned short* __restrict__ Wt,
    float* __restrict__ out)
{
    const int bid = blockIdx.x;
    const int s   = bid >> 3;
    const int r   = (s >> 2) * 8 + (bid & 7);
    if (r >= ROWT) return;
    const int row0 = r * BM;
    const int col0 = (s & 3) * BN;

    __shared__ unsigned short As[2][BM * BK];  // 2 x 8 KB
    __shared__ unsigned short Bs[2][BN * BK];  // 2 x 8 KB

    const int tid  = threadIdx.x;
    const int lane = tid & 63;
    const int wid  = tid >> 6;
    const int wr   = wid >> 1;
    const int wc   = wid & 1;

    f32x4 acc[4][4] = {};

    int srow[2], ksw[2], ldsb[2];
#pragma unroll
    for (int i = 0; i < 2; ++i) {
        const int b   = (i * 256 + tid) * 16;
        const int row = b >> 6;
        const int cir = (b >> 4) & 3;
        srow[i] = row;
        ksw[i]  = (cir ^ ((row >> 1) & 3)) << 3;
        ldsb[i] = b;
    }
    int agr[2];
#pragma unroll
    for (int i = 0; i < 2; ++i) {
        int gr = row0 + srow[i];
        if (gr >= N_NODES) gr = N_NODES - 1;
        agr[i] = gr;
    }

    int abyte[4], bbyte[4];
    const int c = lane >> 4;
#pragma unroll
    for (int m = 0; m < 4; ++m) {
        const int ra = wr * 64 + m * 16 + (lane & 15);
        abyte[m] = ra * 64 + ((c ^ ((ra >> 1) & 3)) << 4);
        const int rb = wc * 64 + m * 16 + (lane & 15);
        bbyte[m] = rb * 64 + ((c ^ ((rb >> 1) & 3)) << 4);
    }

#define STAGE(buf, k0)                                                          \
    do {                                                                        \
        _Pragma("unroll")                                                       \
        for (int i = 0; i < 2; ++i) {                                           \
            gload_lds16(Yb + (size_t)agr[i] * M_IN + (k0) + ksw[i],             \
                        (char*)As[buf] + ldsb[i]);                              \
            gload_lds16(Wt + (size_t)(col0 + srow[i]) * M_IN + (k0) + ksw[i],   \
                        (char*)Bs[buf] + ldsb[i]);                              \
        }                                                                       \
    } while (0)

    STAGE(0, 0);
    asm volatile("s_waitcnt vmcnt(0)" ::: "memory");
    __builtin_amdgcn_s_barrier();

    int cur = 0;
    for (int t = 0; t < NT; ++t) {
        if (t + 1 < NT) STAGE(cur ^ 1, (t + 1) * BK);

        bf16x8 af[4], bfr[4];
#pragma unroll
        for (int m = 0; m < 4; ++m)
            af[m]  = *(const bf16x8*)((const char*)As[cur] + abyte[m]);
#pragma unroll
        for (int n = 0; n < 4; ++n)
            bfr[n] = *(const bf16x8*)((const char*)Bs[cur] + bbyte[n]);

#pragma unroll
        for (int m = 0; m < 4; ++m)
#pragma unroll
            for (int n = 0; n < 4; ++n)
                acc[m][n] = __builtin_amdgcn_mfma_f32_16x16x32_bf16(
                    af[m], bfr[n], acc[m][n], 0, 0, 0);

        if (t + 1 < NT) {
            asm volatile("s_waitcnt vmcnt(0)" ::: "memory");
            __builtin_amdgcn_s_barrier();
        }
        cur ^= 1;
    }
#undef STAGE

    // epilogue: C/D map col=lane&15, row=(lane>>4)*4+r  [measured m89]
#pragma unroll
    for (int m = 0; m < 4; ++m) {
#pragma unroll
        for (int n = 0; n < 4; ++n) {
#pragma unroll
            for (int rr = 0; rr < 4; ++rr) {
                const int row = row0 + wr * 64 + m * 16 + (lane >> 4) * 4 + rr;
                const int col = col0 + wc * 64 + n * 16 + (lane & 15);
                if (row < N_NODES)
                    out[(size_t)row * H_OUT + col] = fmaxf(acc[m][n][rr], 0.f);
            }
        }
    }
}

extern "C" void kernel_launch(void* const* d_in, const int* in_sizes, int n_in,
                              void* d_out, int out_size, void* d_ws, size_t ws_size,
                              hipStream_t stream) {
    const float* X    = (const float*)d_in[0];
    const float* W    = (const float*)d_in[1];
    const int*   esrc = (const int*)d_in[2];
    const int*   edst = (const int*)d_in[3];
    const float* eval = (const float*)d_in[4];
    float* out = (float*)d_out;

    // workspace layout (16B-aligned)
    char* w = (char*)d_ws;
    unsigned short* Yb = (unsigned short*)w;  w += (size_t)N_NODES * M_IN * 2;  // 51.2 MB
    unsigned char*  Xq = (unsigned char*)w;   w += (size_t)N_NODES * M_IN;      // 25.6 MB
    float*          sc = (float*)w;           w += (size_t)N_NODES * 4;         // 200 KB
    unsigned short* Wt = (unsigned short*)w;  w += (size_t)M_IN * H_OUT * 2;    // 0.5 MB
    int*   offs   = (int*)w;                  w += (size_t)(N_NODES + 4) * 4;   // 16B align
    int*   cursor = (int*)w;                  w += (size_t)N_NODES * 4;
    int*   bsum   = (int*)w;                  w += (size_t)((SCAN_B + 3) & ~3) * 4;
    int*   hrep   = (int*)w;                  w += (size_t)8 * HPAD * 4;        // 1.6 MB
    unsigned int* pairs = (unsigned int*)w;                                     // 3.2 MB

    hipMemsetAsync(hrep, 0, (size_t)8 * HPAD * sizeof(int), stream);

    prep_kernel<<<CONVX_B + CONVW_B + HIST_B, 256, 0, stream>>>(
        X, Xq, sc, W, Wt, edst, hrep);

    scan1_kernel<<<SCAN_B, 256, 0, stream>>>(hrep, cursor, bsum);
    scan3_kernel<<<SCAN_B, 256, 0, stream>>>(cursor, bsum, offs);  // cursor := offs

    build_kernel<<<(N_EDGES + 255) / 256, 256, 0, stream>>>(
        esrc, edst, eval, cursor, pairs);

    // one wave per node: 12500 blocks x 4 waves
    gather_kernel<<<(N_NODES + 3) / 4, 256, 0, stream>>>(Xq, sc, offs, pairs, Yb);

    gemm_mfma_kernel<<<GEMM_GRID, 256, 0, stream>>>(Yb, Wt, out);
}